// Round 12
// baseline (1079.279 us; speedup 1.0000x reference)
//
#include <hip/hip_runtime.h>
#include <hip/hip_bf16.h>

#define EMB_D 100
#define HID 64
#define G4 256
#define BATCH 128
#define SEQ 1024
#define TOK 64

typedef _Float16 half2v __attribute__((ext_vector_type(2)));
typedef unsigned short u16;
typedef unsigned int   u32;

__device__ __forceinline__ float sigf(float x) { return 1.0f / (1.0f + __expf(-x)); }
__device__ __forceinline__ float tanh_fast(float x) {
  float t = __expf(-2.0f * fabsf(x));
  float r = (1.0f - t) / (1.0f + t);
  return copysignf(r, x);
}
__device__ __forceinline__ float dot2(u32 h, u32 w, float acc) {
  return __builtin_amdgcn_fdot2(__builtin_bit_cast(half2v, h),
                                __builtin_bit_cast(half2v, w), acc, false);
}
__device__ __forceinline__ u32 packh2(float lo, float hi) {
  u16 a = __builtin_bit_cast(u16, (_Float16)lo);
  u16 b = __builtin_bit_cast(u16, (_Float16)hi);
  return (u32)a | ((u32)b << 16);
}
#define QPERM_X1(x)                                                           \
  __builtin_bit_cast(float, __builtin_amdgcn_mov_dpp(                         \
      __builtin_bit_cast(int, (x)), 0xB1, 0xF, 0xF, true))

// 16 dot2: 4 uint4 h-chunks (32 f16) x 4 uint4 weight chunks -> one gate half
__device__ __forceinline__ float gdot(const uint4 hc[4], const uint4 wg[4]) {
  float a0 = 0.f, a1 = 0.f, a2 = 0.f, a3 = 0.f;
  #pragma unroll
  for (int c = 0; c < 4; ++c) {
    a0 = dot2(hc[c].x, wg[c].x, a0);
    a1 = dot2(hc[c].y, wg[c].y, a1);
    a2 = dot2(hc[c].z, wg[c].z, a2);
    a3 = dot2(hc[c].w, wg[c].w, a3);
  }
  return (a0 + a1) + (a2 + a3);
}

// --- prep: biases, f16-pair-packed Wih0 (transposed), packed recurrent W ---
__global__ void prep_kernel(const float* __restrict__ Wih0,
                            const float* __restrict__ Whh0, const float* __restrict__ Wih1,
                            const float* __restrict__ Whh1,
                            const float* __restrict__ bih0, const float* __restrict__ bhh0,
                            const float* __restrict__ bih1, const float* __restrict__ bhh1,
                            u32* __restrict__ Wih0T2, float* __restrict__ b0c,
                            float* __restrict__ b1c,
                            u32* __restrict__ Whh0h, u32* __restrict__ Wih1h,
                            u32* __restrict__ Whh1h) {
  int g = threadIdx.x;   // 0..255 = gate row
  b0c[g] = bih0[g] + bhh0[g];
  b1c[g] = bih1[g] + bhh1[g];
  for (int dp = 0; dp < 50; ++dp)
    Wih0T2[dp * G4 + g] = packh2(Wih0[g * EMB_D + 2 * dp], Wih0[g * EMB_D + 2 * dp + 1]);
  for (int d = 0; d < 32; ++d) {
    Whh0h[g * 32 + d] = packh2(Whh0[g * HID + 2 * d], Whh0[g * HID + 2 * d + 1]);
    Wih1h[g * 32 + d] = packh2(Wih1[g * HID + 2 * d], Wih1[g * HID + 2 * d + 1]);
    Whh1h[g * 32 + d] = packh2(Whh1[g * HID + 2 * d], Whh1[g * HID + 2 * d + 1]);
  }
}

// --- xw0: f16 dot2 GEMV; output layout [t][element][gate] (4 contig f16) ---
__global__ __attribute__((amdgpu_waves_per_eu(1, 4))) __launch_bounds__(256)
void xw0_kernel(
    const int* __restrict__ x, const float* __restrict__ emb,
    const u32* __restrict__ Wih0T2, const float* __restrict__ b0c,
    u16* __restrict__ xwP) {
  __shared__ int sidx[TOK];
  __shared__ alignas(16) u32 erow[TOK][52];
  int g = threadIdx.x;
  long t0 = (long)blockIdx.x * TOK;

  if (g < TOK) sidx[g] = x[t0 + g];
  __syncthreads();
  for (int i = g; i < TOK * 50; i += 256) {
    int tok = i / 50, dp = i - tok * 50;
    const float* er = emb + (size_t)sidx[tok] * EMB_D + 2 * dp;
    erow[tok][dp] = packh2(er[0], er[1]);
  }
  for (int i = g; i < TOK * 2; i += 256) erow[i >> 1][50 + (i & 1)] = 0;

  u32 wreg[52];
  #pragma unroll
  for (int dp = 0; dp < 50; ++dp) wreg[dp] = Wih0T2[dp * G4 + g];
  wreg[50] = 0; wreg[51] = 0;
  float bb = b0c[g];
  __syncthreads();

  const int e = g & 63, q = g >> 6;
  for (int tok = 0; tok < TOK; ++tok) {
    const uint4* ep = (const uint4*)erow[tok];
    float a0 = bb, a1 = 0.f, a2 = 0.f, a3 = 0.f;
    #pragma unroll
    for (int c = 0; c < 13; ++c) {
      uint4 hv = ep[c];
      a0 = dot2(hv.x, wreg[4 * c],     a0);
      a1 = dot2(hv.y, wreg[4 * c + 1], a1);
      a2 = dot2(hv.z, wreg[4 * c + 2], a2);
      a3 = dot2(hv.w, wreg[4 * c + 3], a3);
    }
    xwP[((size_t)(t0 + tok)) * G4 + e * 4 + q] =
        __builtin_bit_cast(u16, (_Float16)((a0 + a1) + (a2 + a3)));
  }
}

// --- fused recurrence: 6 waves (K-split x 2 per role), 2 barriers/step ---
// Roles: A(w0,w1)=Whh0@h0+L0act, B(w2,w3)=Wih1@h0 (lag-1 ps), C(w4,w5)=
// Whh1@h1+L1act. Lane l owns element l's quartet (rows l,l+64,l+128,l+192),
// K-half s=w&1 -> 64 weight u32/lane (fits registers, no spill possible).
// Phase1: dots -> partials (A1/B0/B1/C1 write LDS, A0/C0 keep regs).
// Phase2: A0 combines own+pa1+xw -> h0_t; C0 combines own+pc1+ps(lag1)+bias
// -> h1_{t-2}. Activation lane-local. xw: depth-4 reg FIFO (unroll-4).
__global__ __attribute__((amdgpu_waves_per_eu(1, 2))) __launch_bounds__(384)
void lstm_fused_kernel(
    const u16* __restrict__ xwP,
    const u32* __restrict__ Whh0h, const u32* __restrict__ Wih1h,
    const u32* __restrict__ Whh1h, const float* __restrict__ b1c,
    const float* __restrict__ W1, const float* __restrict__ clsb1,
    const float* __restrict__ W2, const float* __restrict__ clsb2,
    float* __restrict__ out) {
  const int tid = threadIdx.x;
  const int l = tid & 63;
  const int w = tid >> 6;         // 0..5
  const int role = w >> 1;        // 0=A,1=B,2=C
  const int s = w & 1;            // K-half
  const int b = blockIdx.x;

  __shared__ alignas(16) _Float16 h0s[2][HID];
  __shared__ alignas(16) _Float16 h1s[HID];
  __shared__ float pa1[4][HID];
  __shared__ float pc1[4][HID];
  __shared__ float ps0[2][4][HID];
  __shared__ float ps1[2][4][HID];
  __shared__ alignas(16) float hf[HID];

  // 64 weight u32 per lane: 4 rows x 4 uint4 (half-K)
  const u32* wsrc = (role == 0) ? Whh0h : (role == 1) ? Wih1h : Whh1h;
  uint4 wv[4][4];
  #pragma unroll
  for (int g = 0; g < 4; ++g) {
    const uint4* p = (const uint4*)(wsrc + (l + 64 * g) * 32 + 16 * s);
    #pragma unroll
    for (int c = 0; c < 4; ++c) wv[g][c] = p[c];
  }
  #pragma unroll
  for (int g = 0; g < 4; ++g)
    #pragma unroll
    for (int c = 0; c < 4; ++c)
      asm volatile("" : "+v"(wv[g][c].x), "+v"(wv[g][c].y),
                        "+v"(wv[g][c].z), "+v"(wv[g][c].w));

  float bias0 = 0.f, bias1 = 0.f, bias2 = 0.f, bias3 = 0.f;
  if (w == 4) {
    bias0 = b1c[l]; bias1 = b1c[l + 64]; bias2 = b1c[l + 128]; bias3 = b1c[l + 192];
  }

  float c_reg = 0.f;
  const u16* xb = xwP + (size_t)b * SEQ * G4;
  uint2 xq[4];
  if (w == 0) {
    #pragma unroll
    for (int u = 0; u < 4; ++u) xq[u] = *(const uint2*)(xb + (size_t)u * G4 + l * 4);
  }

  if (tid < 128) ((u16*)h0s)[tid] = 0;
  else if (tid < 192) ((u16*)h1s)[tid - 128] = 0;
  __syncthreads();

  float own0 = 0.f, own1 = 0.f, own2 = 0.f, own3 = 0.f;

  auto phase1 = [&](int t) {
    const int rb = (t + 1) & 1, wbuf = t & 1;
    const bool active = (role == 0) ? (t < SEQ)
                      : (role == 1) ? (t >= 1 && t <= SEQ)
                                    : (t >= 2 && t <= SEQ + 1);
    if (active) {
      uint4 hc[4];
      const _Float16* hsrc = (role == 2) ? h1s : h0s[rb];
      const uint4* hp = (const uint4*)(hsrc + 32 * s);
      #pragma unroll
      for (int c = 0; c < 4; ++c) hc[c] = hp[c];
      own0 = gdot(hc, wv[0]);
      own1 = gdot(hc, wv[1]);
      own2 = gdot(hc, wv[2]);
      own3 = gdot(hc, wv[3]);
      if (w == 1) {
        pa1[0][l] = own0; pa1[1][l] = own1; pa1[2][l] = own2; pa1[3][l] = own3;
      } else if (w == 2) {
        ps0[wbuf][0][l] = own0; ps0[wbuf][1][l] = own1;
        ps0[wbuf][2][l] = own2; ps0[wbuf][3][l] = own3;
      } else if (w == 3) {
        ps1[wbuf][0][l] = own0; ps1[wbuf][1][l] = own1;
        ps1[wbuf][2][l] = own2; ps1[wbuf][3][l] = own3;
      } else if (w == 5) {
        pc1[0][l] = own0; pc1[1][l] = own1; pc1[2][l] = own2; pc1[3][l] = own3;
      }
    }
  };

  auto phase2 = [&](int t, int u) {
    const int rb = (t + 1) & 1, wbuf = t & 1;
    if (w == 0) {
      if (t < SEQ) {
        half2v xif = __builtin_bit_cast(half2v, xq[u].x);
        half2v xgo = __builtin_bit_cast(half2v, xq[u].y);
        float gi = own0 + pa1[0][l] + (float)xif[0];
        float gf = own1 + pa1[1][l] + (float)xif[1];
        float gg = own2 + pa1[2][l] + (float)xgo[0];
        float go = own3 + pa1[3][l] + (float)xgo[1];
        c_reg = sigf(gf) * c_reg + sigf(gi) * tanh_fast(gg);
        float hv = sigf(go) * tanh_fast(c_reg);
        float nb = QPERM_X1(hv);
        if (!(l & 1)) ((u32*)h0s[wbuf])[l >> 1] = packh2(hv, nb);
        int tn = t + 4; if (tn > SEQ - 1) tn = SEQ - 1;
        xq[u] = *(const uint2*)(xb + (size_t)tn * G4 + l * 4);
      }
    } else if (w == 4) {
      if (t >= 2 && t <= SEQ + 1) {
        float gi = own0 + pc1[0][l] + ps0[rb][0][l] + ps1[rb][0][l] + bias0;
        float gf = own1 + pc1[1][l] + ps0[rb][1][l] + ps1[rb][1][l] + bias1;
        float gg = own2 + pc1[2][l] + ps0[rb][2][l] + ps1[rb][2][l] + bias2;
        float go = own3 + pc1[3][l] + ps0[rb][3][l] + ps1[rb][3][l] + bias3;
        c_reg = sigf(gf) * c_reg + sigf(gi) * tanh_fast(gg);
        float hv = sigf(go) * tanh_fast(c_reg);
        float nb = QPERM_X1(hv);
        if (!(l & 1)) ((u32*)h1s)[l >> 1] = packh2(hv, nb);
        if (t == SEQ + 1) hf[l] = hv;
      }
    }
  };

  for (int tb = 0; tb < SEQ; tb += 4) {
    #pragma unroll
    for (int u = 0; u < 4; ++u) {
      const int t = tb + u;
      phase1(t);
      asm volatile("s_waitcnt lgkmcnt(0)" ::: "memory");
      __builtin_amdgcn_s_barrier();
      phase2(t, u);
      asm volatile("s_waitcnt lgkmcnt(0)" ::: "memory");
      __builtin_amdgcn_s_barrier();
    }
  }
  #pragma unroll
  for (int te = SEQ; te <= SEQ + 1; ++te) {
    phase1(te);
    asm volatile("s_waitcnt lgkmcnt(0)" ::: "memory");
    __builtin_amdgcn_s_barrier();
    phase2(te, 0);
    asm volatile("s_waitcnt lgkmcnt(0)" ::: "memory");
    __builtin_amdgcn_s_barrier();
  }
  __syncthreads();

  // classifier (wave 0): z = relu(h1.W1^T + b1); out = sigmoid(z.W2 + b2)
  if (w == 0) {
    int j = l;
    const float4* wp = (const float4*)(W1 + j * HID);
    const float4* hp = (const float4*)hf;
    float z0 = clsb1[j], z1 = 0.f, z2 = 0.f, z3 = 0.f;
    #pragma unroll
    for (int cc = 0; cc < 16; ++cc) {
      float4 wvv = wp[cc];
      float4 hv = hp[cc];
      z0 = fmaf(hv.x, wvv.x, z0);
      z1 = fmaf(hv.y, wvv.y, z1);
      z2 = fmaf(hv.z, wvv.z, z2);
      z3 = fmaf(hv.w, wvv.w, z3);
    }
    float z = fmaxf((z0 + z1) + (z2 + z3), 0.f);
    float v = z * W2[j];
    v += __shfl_xor(v, 1);
    v += __shfl_xor(v, 2);
    v += __shfl_xor(v, 4);
    v += __shfl_xor(v, 8);
    v += __shfl_xor(v, 16);
    v += __shfl_xor(v, 32);
    if (l == 0) out[b] = sigf(v + clsb2[0]);
  }
}

extern "C" void kernel_launch(void* const* d_in, const int* in_sizes, int n_in,
                              void* d_out, int out_size, void* d_ws, size_t ws_size,
                              hipStream_t stream) {
  const int*   x    = (const int*)d_in[0];
  const float* emb  = (const float*)d_in[1];
  const float* Wih0 = (const float*)d_in[2];
  const float* Whh0 = (const float*)d_in[3];
  const float* bih0 = (const float*)d_in[4];
  const float* bhh0 = (const float*)d_in[5];
  const float* Wih1 = (const float*)d_in[6];
  const float* Whh1 = (const float*)d_in[7];
  const float* bih1 = (const float*)d_in[8];
  const float* bhh1 = (const float*)d_in[9];
  const float* W1   = (const float*)d_in[10];
  const float* b1   = (const float*)d_in[11];
  const float* W2   = (const float*)d_in[12];
  const float* b2   = (const float*)d_in[13];
  float* out = (float*)d_out;

  char* ws = (char*)d_ws;
  const size_t XW0_BYTES = (size_t)BATCH * SEQ * G4 * sizeof(u16);  // 67108864
  u16* xwP    = (u16*)ws;       ws += XW0_BYTES;
  u32* Wih0T2 = (u32*)ws;       ws += (size_t)50 * G4 * sizeof(u32);
  float* b0c  = (float*)ws;     ws += G4 * sizeof(float);
  float* b1c  = (float*)ws;     ws += G4 * sizeof(float);
  u32* Whh0h  = (u32*)ws;       ws += (size_t)G4 * 32 * sizeof(u32);
  u32* Wih1h  = (u32*)ws;       ws += (size_t)G4 * 32 * sizeof(u32);
  u32* Whh1h  = (u32*)ws;       ws += (size_t)G4 * 32 * sizeof(u32);

  prep_kernel<<<1, 256, 0, stream>>>(Wih0, Whh0, Wih1, Whh1, bih0, bhh0, bih1, bhh1,
                                     Wih0T2, b0c, b1c, Whh0h, Wih1h, Whh1h);
  xw0_kernel<<<(BATCH * SEQ) / TOK, 256, 0, stream>>>(x, emb, Wih0T2, b0c, xwP);
  lstm_fused_kernel<<<BATCH, 384, 0, stream>>>(xwP, Whh0h, Wih1h, Whh1h, b1c,
                                               W1, b1, W2, b2, out);
}